// Round 11
// baseline (864.724 us; speedup 1.0000x reference)
//
#include <hip/hip_runtime.h>
#include <hip/hip_bf16.h>

#define M_TOT 8192
#define N_TOT 16384
#define K_TOT 4096
#define NT (K_TOT / 64)  // 64 K-tiles of BK=64

typedef int i32x4 __attribute__((ext_vector_type(4)));
typedef int i32x16 __attribute__((ext_vector_type(16)));
typedef __bf16 bf16x8 __attribute__((ext_vector_type(8)));
typedef float f32x4 __attribute__((ext_vector_type(4)));

__device__ __forceinline__ ushort f2bf_rne(float f) {
  unsigned u = __float_as_uint(f);
  u += 0x7FFFu + ((u >> 16) & 1u);
  return (ushort)(u >> 16);
}
__device__ __forceinline__ ushort sgn_bf16(float w) {
  return w > 0.f ? (ushort)0x3F80u : (w < 0.f ? (ushort)0xBF80u : (ushort)0u);
}

// ============ Fragment-order (tiled) operand layouts (R10-verified) ========
// A_tiled: 1KB chunk (r32, kt, ks) at (r32*128 + kt*2 + ks)*1024; lane l
//   holds A[r32*32 + (l&31)][kt*64 + ks*32 + (l>>5)*16 .. +16).  (33.5 MB)
// B_tiled: same form with n32 = col-block: (n32*128 + kt*2 + ks)*1024. (67 MB)
// These ARE the mfma_i32_32x32x32_i8 operand fragments -> all GEMM loads are
// lane-linear 1KB buffer loads (perfectly coalesced), no shuffle, no LDS.

// ---------------- pass 1a: per-row amax + quantize x -> A_tiled --------------
__global__ void quant_x_kernel(const float* __restrict__ x,
                               char* __restrict__ At, float* __restrict__ s) {
  int row = blockIdx.x;
  int tid = threadIdx.x;
  const float4* xr = (const float4*)(x + (size_t)row * K_TOT + tid * 16);
  float4 v[4];
  float amax = 0.f;
#pragma unroll
  for (int j = 0; j < 4; ++j) {
    v[j] = xr[j];  // 16 contiguous floats per thread (64B)
    amax = fmaxf(amax, fmaxf(fmaxf(fabsf(v[j].x), fabsf(v[j].y)),
                             fmaxf(fabsf(v[j].z), fabsf(v[j].w))));
  }
#pragma unroll
  for (int o = 32; o > 0; o >>= 1) amax = fmaxf(amax, __shfl_xor(amax, o));
  __shared__ float wmax[4];
  if ((tid & 63) == 0) wmax[tid >> 6] = amax;
  __syncthreads();
  amax = fmaxf(fmaxf(wmax[0], wmax[1]), fmaxf(wmax[2], wmax[3]));
  float inv = amax > 0.f ? 127.0f / amax : 0.f;
  if (tid == 0) s[row] = amax * (1.0f / 127.0f);
  int q[16];
#pragma unroll
  for (int j = 0; j < 4; ++j) {
    q[j * 4 + 0] = max(-127, min(127, __float2int_rn(v[j].x * inv)));
    q[j * 4 + 1] = max(-127, min(127, __float2int_rn(v[j].y * inv)));
    q[j * 4 + 2] = max(-127, min(127, __float2int_rn(v[j].z * inv)));
    q[j * 4 + 3] = max(-127, min(127, __float2int_rn(v[j].w * inv)));
  }
  int4 o4;
  int* op = (int*)&o4;
#pragma unroll
  for (int j = 0; j < 4; ++j)
    op[j] = (q[j * 4] & 255) | ((q[j * 4 + 1] & 255) << 8) |
            ((q[j * 4 + 2] & 255) << 16) | ((q[j * 4 + 3] & 255) << 24);
  int r32 = row >> 5, l31 = row & 31;
  int kt = tid >> 2, ks = (tid >> 1) & 1, hi = tid & 1;
  size_t dst = ((size_t)(r32 * 128 + kt * 2 + ks) << 10) + ((hi * 32 + l31) << 4);
  *(int4*)(At + dst) = o4;
}

// ---------------- pass 1b: W -> sign i8 in B_tiled ----------------
__global__ void quant_w_kernel(const float* __restrict__ w,
                               char* __restrict__ Bt) {
  int n32 = blockIdx.x;  // 512 blocks
  int t = threadIdx.x;
#pragma unroll 4
  for (int i = 0; i < 32; ++i) {
    int c = i * 256 + t;  // chunk16 index 0..8191 within this n32 slab
    int kt = c >> 7, ks = (c >> 6) & 1, l = c & 63;
    int n = n32 * 32 + (l & 31);
    int k = kt * 64 + ks * 32 + (l >> 5) * 16;
    const float4* src = (const float4*)(w + (size_t)n * K_TOT + k);
    int4 o4;
    int* op = (int*)&o4;
#pragma unroll
    for (int j = 0; j < 4; ++j) {
      float4 v = src[j];
      int q0 = v.x > 0.f ? 1 : (v.x < 0.f ? -1 : 0);
      int q1 = v.y > 0.f ? 1 : (v.y < 0.f ? -1 : 0);
      int q2 = v.z > 0.f ? 1 : (v.z < 0.f ? -1 : 0);
      int q3 = v.w > 0.f ? 1 : (v.w < 0.f ? -1 : 0);
      op[j] = (q0 & 255) | ((q1 & 255) << 8) | ((q2 & 255) << 16) |
              ((q3 & 255) << 24);
    }
    *(int4*)(Bt + ((size_t)n32 << 17) + ((size_t)c << 4)) = o4;
  }
}

// ---------------- pass 2: pure-register i8 GEMM — no LDS, no barriers -------
// C[m][n] = s[m]*(sum_k A8[m][k]*W8[n][k]) + bias[n]  (i32 accum, exact)
// 256 threads = 4 INDEPENDENT waves; each wave owns a 128x64 output tile
// (4mi x 2ni of 32x32; acc 128 AGPR). Per K-tile (BK=64): 12 coalesced
// global_load_dwordx4 (1KB each: A 8, B 4) straight into registers + 16 MFMA.
// Double-buffered reg sets (P/Q, static names), unroll-2; NO s_barrier, NO
// LDS -> waves drift freely, 2 waves/SIMD keep the matrix pipe fed. Plain
// loads are compiler-tracked: hipcc emits counted s_waitcnt vmcnt(12) before
// each set's first MFMA use (prefetch slack = one tile of MFMA ~585 cyc).
// Block's 4 waves share bm (same A panel -> L1/L2 hits), bn = bnq*4+wave.
// XCD supertile: each XCD gets 32bm x 16bnq (4096x4096 output; A,B slices
// 16.8 MB each) for joint L2/L3 locality.
__global__ __launch_bounds__(256, 2) void gemm_i8_pure(
    const char* __restrict__ At, const char* __restrict__ Bt,
    const float* __restrict__ s, const float* __restrict__ bias,
    float* __restrict__ C) {
  int bid = blockIdx.x;
  int xcd = bid & 7;
  int loc = bid >> 3;                      // 0..511 within XCD
  int bm = (xcd >> 2) * 32 + (loc & 31);   // 0..63  (128-row tile)
  int bnq = (xcd & 3) * 16 + (loc >> 5);   // 0..63  (256-col quad)
  int lane = threadIdx.x & 63;
  int wave = threadIdx.x >> 6;
  int bn_w = bnq * 4 + wave;               // 0..255 (64-col wave tile)
  int rowBase = bm * 128;
  int colBase = bn_w * 64;
  int l31 = lane & 31;
  int hi = lane >> 5;

  const char* pA0 = At + (((size_t)(bm * 4 + 0) * 128) << 10) + (lane << 4);
  const char* pA1 = pA0 + (128 << 10);
  const char* pA2 = pA0 + (256 << 10);
  const char* pA3 = pA0 + (384 << 10);
  const char* pB0 = Bt + (((size_t)(bn_w * 2 + 0) * 128) << 10) + (lane << 4);
  const char* pB1 = pB0 + (128 << 10);

  i32x16 acc[4][2] = {};
  i32x4 aP[4][2], bP[2][2], aQ[4][2], bQ[2][2];

#define LOADSET(AS, BS, O)                                                    \
  {                                                                           \
    AS[0][0] = *(const i32x4*)(pA0 + (O));                                    \
    AS[0][1] = *(const i32x4*)(pA0 + (O) + 1024);                             \
    AS[1][0] = *(const i32x4*)(pA1 + (O));                                    \
    AS[1][1] = *(const i32x4*)(pA1 + (O) + 1024);                             \
    AS[2][0] = *(const i32x4*)(pA2 + (O));                                    \
    AS[2][1] = *(const i32x4*)(pA2 + (O) + 1024);                             \
    AS[3][0] = *(const i32x4*)(pA3 + (O));                                    \
    AS[3][1] = *(const i32x4*)(pA3 + (O) + 1024);                             \
    BS[0][0] = *(const i32x4*)(pB0 + (O));                                    \
    BS[0][1] = *(const i32x4*)(pB0 + (O) + 1024);                             \
    BS[1][0] = *(const i32x4*)(pB1 + (O));                                    \
    BS[1][1] = *(const i32x4*)(pB1 + (O) + 1024);                             \
  }
#define MFMASET(AS, BS)                                                       \
  _Pragma("unroll") for (int ks = 0; ks < 2; ++ks)                            \
      _Pragma("unroll") for (int mi = 0; mi < 4; ++mi)                        \
          _Pragma("unroll") for (int ni = 0; ni < 2; ++ni)                    \
              acc[mi][ni] = __builtin_amdgcn_mfma_i32_32x32x32_i8(            \
                  AS[mi][ks], BS[ni][ks], acc[mi][ni], 0, 0, 0);

  LOADSET(aP, bP, 0);  // tile 0
  for (int it = 0; it < 31; ++it) {
    LOADSET(aQ, bQ, 2048);  // tile 2it+1 (prefetch)
    MFMASET(aP, bP);        // consume tile 2it
    pA0 += 4096; pA1 += 4096; pA2 += 4096; pA3 += 4096;
    pB0 += 4096; pB1 += 4096;
    LOADSET(aP, bP, 0);     // tile 2it+2 (prefetch)
    MFMASET(aQ, bQ);        // consume tile 2it+1
  }
  LOADSET(aQ, bQ, 2048);    // tile 63
  MFMASET(aP, bP);          // tile 62
  MFMASET(aQ, bQ);          // tile 63

#undef MFMASET
#undef LOADSET

  // epilogue: y = s[m] * acc + bias[n]
  // C/D 32x32: col = lane&31, row = (reg&3) + 8*(reg>>2) + 4*(lane>>5)
#pragma unroll
  for (int mi = 0; mi < 4; ++mi) {
#pragma unroll
    for (int ni = 0; ni < 2; ++ni) {
      int gc = colBase + ni * 32 + l31;
      float bv = bias[gc];
#pragma unroll
      for (int rg = 0; rg < 16; ++rg) {
        int rowIn = (rg & 3) + 8 * (rg >> 2) + 4 * hi;
        int gr = rowBase + mi * 32 + rowIn;
        C[(size_t)gr * N_TOT + gc] = (float)acc[mi][ni][rg] * s[gr] + bv;
      }
    }
  }
}

// ---------------- fallback (ws too small): fused bf16 conversion GEMM --------
__global__ void gemm_fused_kernel(const float* __restrict__ A,
                                  const float* __restrict__ W,
                                  const float* __restrict__ bias,
                                  float* __restrict__ C) {
  __shared__ ushort lsA[128 * 32];
  __shared__ ushort lsB[128 * 32];

  int nwg = gridDim.x;
  int bid = blockIdx.x;
  int wg = (bid & 7) * (nwg >> 3) + (bid >> 3);
  const int NBN = N_TOT / 128;
  int bm = wg / NBN;
  int bn = wg % NBN;
  int rowBase = bm * 128;
  int colBase = bn * 128;

  int t = threadIdx.x;
  int lane = t & 63;
  int wave = t >> 6;
  int wm = (wave >> 1) * 64;
  int wn = (wave & 1) * 64;

  f32x4 acc[4][4] = {};

  int srow = t >> 3;
  int scol = (t & 7) * 4;
  int fr = lane & 15;
  int koff = (lane >> 4) * 8;

  for (int k0 = 0; k0 < K_TOT; k0 += 32) {
    float4 va[4], vb[4];
#pragma unroll
    for (int r = 0; r < 4; ++r) {
      va[r] = *(const float4*)&A[(size_t)(rowBase + r * 32 + srow) * K_TOT + k0 + scol];
      vb[r] = *(const float4*)&W[(size_t)(colBase + r * 32 + srow) * K_TOT + k0 + scol];
    }
    __syncthreads();
#pragma unroll
    for (int r = 0; r < 4; ++r) {
      int e = r * 1024 + t * 4;
      ushort4 oa, ob;
      oa.x = f2bf_rne(va[r].x); oa.y = f2bf_rne(va[r].y);
      oa.z = f2bf_rne(va[r].z); oa.w = f2bf_rne(va[r].w);
      ob.x = sgn_bf16(vb[r].x); ob.y = sgn_bf16(vb[r].y);
      ob.z = sgn_bf16(vb[r].z); ob.w = sgn_bf16(vb[r].w);
      *(ushort4*)&lsA[e] = oa;
      *(ushort4*)&lsB[e] = ob;
    }
    __syncthreads();

    bf16x8 af[4], bfr[4];
#pragma unroll
    for (int i = 0; i < 4; ++i)
      af[i] = *(const bf16x8*)&lsA[(wm + i * 16 + fr) * 32 + koff];
#pragma unroll
    for (int j = 0; j < 4; ++j)
      bfr[j] = *(const bf16x8*)&lsB[(wn + j * 16 + fr) * 32 + koff];

#pragma unroll
    for (int i = 0; i < 4; ++i)
#pragma unroll
      for (int j = 0; j < 4; ++j)
        acc[i][j] = __builtin_amdgcn_mfma_f32_16x16x32_bf16(af[i], bfr[j],
                                                            acc[i][j], 0, 0, 0);
  }

  int orow0 = rowBase + wm + ((lane >> 4) << 2);
  int ocol0 = colBase + wn + (lane & 15);
#pragma unroll
  for (int i = 0; i < 4; ++i) {
#pragma unroll
    for (int j = 0; j < 4; ++j) {
      int col = ocol0 + j * 16;
      float bv = bias[col];
#pragma unroll
      for (int rg = 0; rg < 4; ++rg) {
        int row = orow0 + i * 16 + rg;
        C[(size_t)row * N_TOT + col] = acc[i][j][rg] + bv;
      }
    }
  }
}

extern "C" void kernel_launch(void* const* d_in, const int* in_sizes, int n_in,
                              void* d_out, int out_size, void* d_ws,
                              size_t ws_size, hipStream_t stream) {
  const float* x = (const float*)d_in[0];
  const float* W = (const float*)d_in[1];
  const float* b = (const float*)d_in[2];
  float* out = (float*)d_out;

  const size_t xq_bytes = (size_t)M_TOT * K_TOT;           // 33.5 MB
  const size_t wq_bytes = (size_t)N_TOT * K_TOT;           // 67.1 MB
  const size_t need = xq_bytes + wq_bytes + M_TOT * 4;     // ~101 MB

  if (ws_size >= need) {
    char* At = (char*)d_ws;
    char* Bt = At + xq_bytes;
    float* s = (float*)(Bt + wq_bytes);
    quant_x_kernel<<<M_TOT, 256, 0, stream>>>(x, At, s);
    quant_w_kernel<<<N_TOT / 32, 256, 0, stream>>>(W, Bt);
    gemm_i8_pure<<<4096, 256, 0, stream>>>(At, Bt, s, b, out);
  } else {
    const int nblocks = (M_TOT / 128) * (N_TOT / 128);
    gemm_fused_kernel<<<nblocks, 256, 0, stream>>>(x, W, b, out);
  }
}

// Round 12
// 782.560 us; speedup vs baseline: 1.1050x; 1.1050x over previous
//
#include <hip/hip_runtime.h>
#include <hip/hip_bf16.h>

#define M_TOT 8192
#define N_TOT 16384
#define K_TOT 4096
#define NT (K_TOT / 64)  // 64 K-tiles of BK=64

typedef int i32x4 __attribute__((ext_vector_type(4)));
typedef int i32x16 __attribute__((ext_vector_type(16)));
typedef __bf16 bf16x8 __attribute__((ext_vector_type(8)));
typedef float f32x4 __attribute__((ext_vector_type(4)));

#define GLOAD_LDS16(g, l)                                                     \
  __builtin_amdgcn_global_load_lds(                                           \
      (__attribute__((address_space(1))) const void*)(g),                     \
      (__attribute__((address_space(3))) void*)(l), 16, 0, 0)

__device__ __forceinline__ ushort f2bf_rne(float f) {
  unsigned u = __float_as_uint(f);
  u += 0x7FFFu + ((u >> 16) & 1u);
  return (ushort)(u >> 16);
}
__device__ __forceinline__ ushort sgn_bf16(float w) {
  return w > 0.f ? (ushort)0x3F80u : (w < 0.f ? (ushort)0xBF80u : (ushort)0u);
}

// ============ Fragment-order (tiled) operand layouts (R10/R11-verified) =====
// A_tiled: 1KB chunk (r32, kt, ks) at (r32*128 + kt*2 + ks)*1024; lane l
//   holds A[r32*32 + (l&31)][kt*64 + ks*32 + (l>>5)*16 .. +16).  (33.5 MB)
// B_tiled: same with n32: (n32*128 + kt*2 + ks)*1024.  (67 MB)
// These ARE the mfma_i32_32x32x32_i8 operand fragments -> all GEMM-side
// loads are lane-linear (coalesced 1KB; LDS reads conflict-free).

// ---------------- pass 1a: per-row amax + quantize x -> A_tiled --------------
__global__ void quant_x_kernel(const float* __restrict__ x,
                               char* __restrict__ At, float* __restrict__ s) {
  int row = blockIdx.x;
  int tid = threadIdx.x;
  const float4* xr = (const float4*)(x + (size_t)row * K_TOT + tid * 16);
  float4 v[4];
  float amax = 0.f;
#pragma unroll
  for (int j = 0; j < 4; ++j) {
    v[j] = xr[j];
    amax = fmaxf(amax, fmaxf(fmaxf(fabsf(v[j].x), fabsf(v[j].y)),
                             fmaxf(fabsf(v[j].z), fabsf(v[j].w))));
  }
#pragma unroll
  for (int o = 32; o > 0; o >>= 1) amax = fmaxf(amax, __shfl_xor(amax, o));
  __shared__ float wmax[4];
  if ((tid & 63) == 0) wmax[tid >> 6] = amax;
  __syncthreads();
  amax = fmaxf(fmaxf(wmax[0], wmax[1]), fmaxf(wmax[2], wmax[3]));
  float inv = amax > 0.f ? 127.0f / amax : 0.f;
  if (tid == 0) s[row] = amax * (1.0f / 127.0f);
  int q[16];
#pragma unroll
  for (int j = 0; j < 4; ++j) {
    q[j * 4 + 0] = max(-127, min(127, __float2int_rn(v[j].x * inv)));
    q[j * 4 + 1] = max(-127, min(127, __float2int_rn(v[j].y * inv)));
    q[j * 4 + 2] = max(-127, min(127, __float2int_rn(v[j].z * inv)));
    q[j * 4 + 3] = max(-127, min(127, __float2int_rn(v[j].w * inv)));
  }
  int4 o4;
  int* op = (int*)&o4;
#pragma unroll
  for (int j = 0; j < 4; ++j)
    op[j] = (q[j * 4] & 255) | ((q[j * 4 + 1] & 255) << 8) |
            ((q[j * 4 + 2] & 255) << 16) | ((q[j * 4 + 3] & 255) << 24);
  int r32 = row >> 5, l31 = row & 31;
  int kt = tid >> 2, ks = (tid >> 1) & 1, hi = tid & 1;
  size_t dst = ((size_t)(r32 * 128 + kt * 2 + ks) << 10) + ((hi * 32 + l31) << 4);
  *(int4*)(At + dst) = o4;
}

// ---------------- pass 1b: W -> sign i8 in B_tiled ----------------
__global__ void quant_w_kernel(const float* __restrict__ w,
                               char* __restrict__ Bt) {
  int n32 = blockIdx.x;  // 512 blocks
  int t = threadIdx.x;
#pragma unroll 4
  for (int i = 0; i < 32; ++i) {
    int c = i * 256 + t;
    int kt = c >> 7, ks = (c >> 6) & 1, l = c & 63;
    int n = n32 * 32 + (l & 31);
    int k = kt * 64 + ks * 32 + (l >> 5) * 16;
    const float4* src = (const float4*)(w + (size_t)n * K_TOT + k);
    int4 o4;
    int* op = (int*)&o4;
#pragma unroll
    for (int j = 0; j < 4; ++j) {
      float4 v = src[j];
      int q0 = v.x > 0.f ? 1 : (v.x < 0.f ? -1 : 0);
      int q1 = v.y > 0.f ? 1 : (v.y < 0.f ? -1 : 0);
      int q2 = v.z > 0.f ? 1 : (v.z < 0.f ? -1 : 0);
      int q3 = v.w > 0.f ? 1 : (v.w < 0.f ? -1 : 0);
      op[j] = (q0 & 255) | ((q1 & 255) << 8) | ((q2 & 255) << 16) |
              ((q3 & 255) << 24);
    }
    *(int4*)(Bt + ((size_t)n32 << 17) + ((size_t)c << 4)) = o4;
  }
}

// ---------------- pass 2: i8 GEMM — A via LDS, B via regs, NO manual vmcnt --
// C[m][n] = s[m]*(sum_k A8[m][k]*W8[n][k]) + bias[n]  (i32 accum, exact)
// R10 dataflow (best measured: ~640us GEMM) with the explicit stalls removed:
//  - per tile: STAGE_A(t+2 -> buf (t+2)&3) [4 gload_lds]; SCHED_BARRIER(0);
//    LOADB(t+1 -> other reg set) [4 plain loads]; COMPUTE(t) [8 ds_read +
//    16 MFMA, fully compiler-scheduled]; s_barrier; SCHED_BARRIER(0).
//  - NO manual vmcnt in the body. Safety: within each tile STAGE_A issues
//    BEFORE LOADB (pinned by sched_barrier) -> A(t+1)'s gload_lds are OLDER
//    in the vmcnt FIFO than B(t)'s loads; the compiler's own counted vmcnt
//    before B(t)'s first MFMA use (a true data dep) therefore drains
//    A(t+1) too -- before this wave reaches the barrier. All waves cross =>
//    buf(t+1) fully written before any tile-t+1 ds_read. Raw s_barrier adds
//    no vmcnt(0)/lgkmcnt(0) drain (the m97-ceiling mechanism avoided).
//  - sched_barrier(0) after s_barrier pins cross-tile motion (no ds_read
//    hoisted above the barrier, no gload_lds sunk below).
__global__ __launch_bounds__(256, 2) void gemm_i8_hyb(
    const char* __restrict__ At, const char* __restrict__ Bt,
    const float* __restrict__ s, const float* __restrict__ bias,
    float* __restrict__ C) {
  __shared__ char lds[4][16384];

  // XCD stripe swizzle: 4096 blocks (32 bm x 128 bn); stripe = 16 bn x 32 bm.
  int bid = blockIdx.x;
  int wg = (bid & 7) * 512 + (bid >> 3);
  int bnS = wg >> 9;
  int rem = wg & 511;
  int bm = rem >> 4;
  int bn = bnS * 16 + (rem & 15);
  int rowBase = bm * 256;
  int colBase = bn * 128;

  int t = threadIdx.x;
  int lane = t & 63;
  int wave = t >> 6;
  int wr = wave >> 1;  // 0..1 -> M half (128)
  int wc = wave & 1;   // 0..1 -> N half (64)
  int l31 = lane & 31;
  int hi = lane >> 5;

  // A staging sources: LDS group g = ks*8 + rg; thread t covers slots t+256q.
  const char* gAp[4];
#pragma unroll
  for (int q = 0; q < 4; ++q) {
    int ss = t + 256 * q;
    int g = ss >> 6;
    int ks = g >> 3, rg = g & 7;
    gAp[q] = At + ((size_t)((bm * 8 + rg) * 128 + ks) << 10) + ((ss & 63) << 4);
  }
  // B frag bases per ni
  const char* gBp[2];
#pragma unroll
  for (int ni = 0; ni < 2; ++ni)
    gBp[ni] = Bt + ((size_t)(bn * 4 + wc * 2 + ni) << 17) + (lane << 4);

  i32x16 acc[4][2] = {};
  i32x4 brA[2][2], brB[2][2];  // [ks][ni], two static sets

#define STAGE_A(kt_, buf_)                                                    \
  {                                                                           \
    size_t _o = (size_t)(kt_) << 11;                                          \
    GLOAD_LDS16(gAp[0] + _o, &lds[buf_][t * 16]);                             \
    GLOAD_LDS16(gAp[1] + _o, &lds[buf_][4096 + t * 16]);                      \
    GLOAD_LDS16(gAp[2] + _o, &lds[buf_][8192 + t * 16]);                      \
    GLOAD_LDS16(gAp[3] + _o, &lds[buf_][12288 + t * 16]);                     \
  }
#define LOADB(kt_, dst)                                                       \
  {                                                                           \
    size_t _o = (size_t)(kt_) << 11;                                          \
    dst[0][0] = *(const i32x4*)(gBp[0] + _o);                                 \
    dst[0][1] = *(const i32x4*)(gBp[1] + _o);                                 \
    dst[1][0] = *(const i32x4*)(gBp[0] + _o + 1024);                          \
    dst[1][1] = *(const i32x4*)(gBp[1] + _o + 1024);                          \
  }
#define COMPUTE(buf_, bset)                                                   \
  {                                                                           \
    const char* _la = &lds[buf_][0];                                          \
    _Pragma("unroll") for (int ks = 0; ks < 2; ++ks) {                        \
      _Pragma("unroll") for (int mi = 0; mi < 4; ++mi) {                      \
        i32x4 _af = *(const i32x4*)(_la + ((ks * 8 + wr * 4 + mi) << 10) +    \
                                    (lane << 4));                             \
        acc[mi][0] = __builtin_amdgcn_mfma_i32_32x32x32_i8(                   \
            _af, bset[ks][0], acc[mi][0], 0, 0, 0);                           \
        acc[mi][1] = __builtin_amdgcn_mfma_i32_32x32x32_i8(                   \
            _af, bset[ks][1], acc[mi][1], 0, 0, 0);                           \
      }                                                                       \
    }                                                                         \
  }
#define TILE(kt_, buf_, bcur, bnxt)                                           \
  {                                                                           \
    STAGE_A((kt_) + 2, ((buf_) + 2) & 3);                                     \
    __builtin_amdgcn_sched_barrier(0); /* pin: A-stage older than B loads */  \
    LOADB((kt_) + 1, bnxt);                                                   \
    COMPUTE(buf_, bcur);                                                      \
    __builtin_amdgcn_s_barrier();                                             \
    __builtin_amdgcn_sched_barrier(0); /* nothing crosses tile boundary */    \
  }

  // prologue: A(0)->buf0, A(1)->buf1, B(0)->brA; cold drain
  STAGE_A(0, 0);
  STAGE_A(1, 1);
  LOADB(0, brA);
  asm volatile("s_waitcnt vmcnt(0)" ::: "memory");
  __builtin_amdgcn_s_barrier();
  __builtin_amdgcn_sched_barrier(0);

  // main: tiles 0..59 (15 x unroll-4), static buf/set rotation
  for (int it = 0; it < 15; ++it) {
    int kt = it * 4;
    TILE(kt + 0, 0, brA, brB);
    TILE(kt + 1, 1, brB, brA);
    TILE(kt + 2, 2, brA, brB);
    TILE(kt + 3, 3, brB, brA);
  }
  // tail: tiles 60..63 (no staging past A(63), no B past 63)
  {
    STAGE_A(62, 2);
    __builtin_amdgcn_sched_barrier(0);
    LOADB(61, brB);
    COMPUTE(0, brA);
    __builtin_amdgcn_s_barrier();
    __builtin_amdgcn_sched_barrier(0);

    STAGE_A(63, 3);
    __builtin_amdgcn_sched_barrier(0);
    LOADB(62, brA);
    COMPUTE(1, brB);
    __builtin_amdgcn_s_barrier();
    __builtin_amdgcn_sched_barrier(0);

    LOADB(63, brB);
    COMPUTE(2, brA);  // B(62) auto-wait drains A(63) (older in FIFO)
    __builtin_amdgcn_s_barrier();
    __builtin_amdgcn_sched_barrier(0);

    COMPUTE(3, brB);  // B(63) auto-wait
  }

#undef TILE
#undef COMPUTE
#undef LOADB
#undef STAGE_A

  // epilogue: y = s[m] * acc + bias[n]
  // C/D 32x32: col = lane&31, row = (reg&3) + 8*(reg>>2) + 4*(lane>>5)
#pragma unroll
  for (int mi = 0; mi < 4; ++mi) {
#pragma unroll
    for (int ni = 0; ni < 2; ++ni) {
      int gc = colBase + wc * 64 + ni * 32 + l31;
      float bv = bias[gc];
#pragma unroll
      for (int rg = 0; rg < 16; ++rg) {
        int rowIn = (rg & 3) + 8 * (rg >> 2) + 4 * hi;
        int gr = rowBase + wr * 128 + mi * 32 + rowIn;
        C[(size_t)gr * N_TOT + gc] = (float)acc[mi][ni][rg] * s[gr] + bv;
      }
    }
  }
}

// ---------------- fallback (ws too small): fused bf16 conversion GEMM --------
__global__ void gemm_fused_kernel(const float* __restrict__ A,
                                  const float* __restrict__ W,
                                  const float* __restrict__ bias,
                                  float* __restrict__ C) {
  __shared__ ushort lsA[128 * 32];
  __shared__ ushort lsB[128 * 32];

  int nwg = gridDim.x;
  int bid = blockIdx.x;
  int wg = (bid & 7) * (nwg >> 3) + (bid >> 3);
  const int NBN = N_TOT / 128;
  int bm = wg / NBN;
  int bn = wg % NBN;
  int rowBase = bm * 128;
  int colBase = bn * 128;

  int t = threadIdx.x;
  int lane = t & 63;
  int wave = t >> 6;
  int wm = (wave >> 1) * 64;
  int wn = (wave & 1) * 64;

  f32x4 acc[4][4] = {};

  int srow = t >> 3;
  int scol = (t & 7) * 4;
  int fr = lane & 15;
  int koff = (lane >> 4) * 8;

  for (int k0 = 0; k0 < K_TOT; k0 += 32) {
    float4 va[4], vb[4];
#pragma unroll
    for (int r = 0; r < 4; ++r) {
      va[r] = *(const float4*)&A[(size_t)(rowBase + r * 32 + srow) * K_TOT + k0 + scol];
      vb[r] = *(const float4*)&W[(size_t)(colBase + r * 32 + srow) * K_TOT + k0 + scol];
    }
    __syncthreads();
#pragma unroll
    for (int r = 0; r < 4; ++r) {
      int e = r * 1024 + t * 4;
      ushort4 oa, ob;
      oa.x = f2bf_rne(va[r].x); oa.y = f2bf_rne(va[r].y);
      oa.z = f2bf_rne(va[r].z); oa.w = f2bf_rne(va[r].w);
      ob.x = sgn_bf16(vb[r].x); ob.y = sgn_bf16(vb[r].y);
      ob.z = sgn_bf16(vb[r].z); ob.w = sgn_bf16(vb[r].w);
      *(ushort4*)&lsA[e] = oa;
      *(ushort4*)&lsB[e] = ob;
    }
    __syncthreads();

    bf16x8 af[4], bfr[4];
#pragma unroll
    for (int i = 0; i < 4; ++i)
      af[i] = *(const bf16x8*)&lsA[(wm + i * 16 + fr) * 32 + koff];
#pragma unroll
    for (int j = 0; j < 4; ++j)
      bfr[j] = *(const bf16x8*)&lsB[(wn + j * 16 + fr) * 32 + koff];

#pragma unroll
    for (int i = 0; i < 4; ++i)
#pragma unroll
      for (int j = 0; j < 4; ++j)
        acc[i][j] = __builtin_amdgcn_mfma_f32_16x16x32_bf16(af[i], bfr[j],
                                                            acc[i][j], 0, 0, 0);
  }

  int orow0 = rowBase + wm + ((lane >> 4) << 2);
  int ocol0 = colBase + wn + (lane & 15);
#pragma unroll
  for (int i = 0; i < 4; ++i) {
#pragma unroll
    for (int j = 0; j < 4; ++j) {
      int col = ocol0 + j * 16;
      float bv = bias[col];
#pragma unroll
      for (int rg = 0; rg < 4; ++rg) {
        int row = orow0 + i * 16 + rg;
        C[(size_t)row * N_TOT + col] = acc[i][j][rg] + bv;
      }
    }
  }
}

extern "C" void kernel_launch(void* const* d_in, const int* in_sizes, int n_in,
                              void* d_out, int out_size, void* d_ws,
                              size_t ws_size, hipStream_t stream) {
  const float* x = (const float*)d_in[0];
  const float* W = (const float*)d_in[1];
  const float* b = (const float*)d_in[2];
  float* out = (float*)d_out;

  const size_t xq_bytes = (size_t)M_TOT * K_TOT;           // 33.5 MB
  const size_t wq_bytes = (size_t)N_TOT * K_TOT;           // 67.1 MB
  const size_t need = xq_bytes + wq_bytes + M_TOT * 4;     // ~101 MB

  if (ws_size >= need) {
    char* At = (char*)d_ws;
    char* Bt = At + xq_bytes;
    float* s = (float*)(Bt + wq_bytes);
    quant_x_kernel<<<M_TOT, 256, 0, stream>>>(x, At, s);
    quant_w_kernel<<<N_TOT / 32, 256, 0, stream>>>(W, Bt);
    gemm_i8_hyb<<<4096, 256, 0, stream>>>(At, Bt, s, b, out);
  } else {
    const int nblocks = (M_TOT / 128) * (N_TOT / 128);
    gemm_fused_kernel<<<nblocks, 256, 0, stream>>>(x, W, b, out);
  }
}

// Round 14
// 679.943 us; speedup vs baseline: 1.2718x; 1.1509x over previous
//
#include <hip/hip_runtime.h>
#include <hip/hip_bf16.h>

#define M_TOT 8192
#define N_TOT 16384
#define K_TOT 4096
#define NT (K_TOT / 64)  // 64 K-tiles of BK=64

typedef int i32x4 __attribute__((ext_vector_type(4)));
typedef int i32x16 __attribute__((ext_vector_type(16)));
typedef __bf16 bf16x8 __attribute__((ext_vector_type(8)));
typedef float f32x4 __attribute__((ext_vector_type(4)));

#define GLOAD_LDS16(g, l)                                                     \
  __builtin_amdgcn_global_load_lds(                                           \
      (__attribute__((address_space(1))) const void*)(g),                     \
      (__attribute__((address_space(3))) void*)(l), 16, 0, 0)

__device__ __forceinline__ ushort f2bf_rne(float f) {
  unsigned u = __float_as_uint(f);
  u += 0x7FFFu + ((u >> 16) & 1u);
  return (ushort)(u >> 16);
}
__device__ __forceinline__ ushort sgn_bf16(float w) {
  return w > 0.f ? (ushort)0x3F80u : (w < 0.f ? (ushort)0xBF80u : (ushort)0u);
}

// ============ Fragment-order (tiled) operand layouts (R10-verified) =========
// A_tiled: 1KB chunk (r32, kt, ks) at (r32*128 + kt*2 + ks)*1024; lane l
//   holds A[r32*32 + (l&31)][kt*64 + ks*32 + (l>>5)*16 .. +16).  (33.5 MB)
// B_tiled: same with n32: (n32*128 + kt*2 + ks)*1024.  (67 MB)

// ---------------- pass 1a: per-row amax + quantize x -> A_tiled --------------
__global__ void quant_x_kernel(const float* __restrict__ x,
                               char* __restrict__ At, float* __restrict__ s) {
  int row = blockIdx.x;
  int tid = threadIdx.x;
  const float4* xr = (const float4*)(x + (size_t)row * K_TOT + tid * 16);
  float4 v[4];
  float amax = 0.f;
#pragma unroll
  for (int j = 0; j < 4; ++j) {
    v[j] = xr[j];
    amax = fmaxf(amax, fmaxf(fmaxf(fabsf(v[j].x), fabsf(v[j].y)),
                             fmaxf(fabsf(v[j].z), fabsf(v[j].w))));
  }
#pragma unroll
  for (int o = 32; o > 0; o >>= 1) amax = fmaxf(amax, __shfl_xor(amax, o));
  __shared__ float wmax[4];
  if ((tid & 63) == 0) wmax[tid >> 6] = amax;
  __syncthreads();
  amax = fmaxf(fmaxf(wmax[0], wmax[1]), fmaxf(wmax[2], wmax[3]));
  float inv = amax > 0.f ? 127.0f / amax : 0.f;
  if (tid == 0) s[row] = amax * (1.0f / 127.0f);
  int q[16];
#pragma unroll
  for (int j = 0; j < 4; ++j) {
    q[j * 4 + 0] = max(-127, min(127, __float2int_rn(v[j].x * inv)));
    q[j * 4 + 1] = max(-127, min(127, __float2int_rn(v[j].y * inv)));
    q[j * 4 + 2] = max(-127, min(127, __float2int_rn(v[j].z * inv)));
    q[j * 4 + 3] = max(-127, min(127, __float2int_rn(v[j].w * inv)));
  }
  int4 o4;
  int* op = (int*)&o4;
#pragma unroll
  for (int j = 0; j < 4; ++j)
    op[j] = (q[j * 4] & 255) | ((q[j * 4 + 1] & 255) << 8) |
            ((q[j * 4 + 2] & 255) << 16) | ((q[j * 4 + 3] & 255) << 24);
  int r32 = row >> 5, l31 = row & 31;
  int kt = tid >> 2, ks = (tid >> 1) & 1, hi = tid & 1;
  size_t dst = ((size_t)(r32 * 128 + kt * 2 + ks) << 10) + ((hi * 32 + l31) << 4);
  *(int4*)(At + dst) = o4;
}

// ---------------- pass 1b: W -> sign i8 in B_tiled ----------------
__global__ void quant_w_kernel(const float* __restrict__ w,
                               char* __restrict__ Bt) {
  int n32 = blockIdx.x;  // 512 blocks
  int t = threadIdx.x;
#pragma unroll 4
  for (int i = 0; i < 32; ++i) {
    int c = i * 256 + t;
    int kt = c >> 7, ks = (c >> 6) & 1, l = c & 63;
    int n = n32 * 32 + (l & 31);
    int k = kt * 64 + ks * 32 + (l >> 5) * 16;
    const float4* src = (const float4*)(w + (size_t)n * K_TOT + k);
    int4 o4;
    int* op = (int*)&o4;
#pragma unroll
    for (int j = 0; j < 4; ++j) {
      float4 v = src[j];
      int q0 = v.x > 0.f ? 1 : (v.x < 0.f ? -1 : 0);
      int q1 = v.y > 0.f ? 1 : (v.y < 0.f ? -1 : 0);
      int q2 = v.z > 0.f ? 1 : (v.z < 0.f ? -1 : 0);
      int q3 = v.w > 0.f ? 1 : (v.w < 0.f ? -1 : 0);
      op[j] = (q0 & 255) | ((q1 & 255) << 8) | ((q2 & 255) << 16) |
              ((q3 & 255) << 24);
    }
    *(int4*)(Bt + ((size_t)n32 << 17) + ((size_t)c << 4)) = o4;
  }
}

// ---------------- pass 2: i8 GEMM, 256x256 tile, 4-buf LDS, fenced ----------
// C[m][n] = s[m]*(sum_k A8[m][k]*W8[n][k]) + bias[n]  (i32 accum, exact)
// Traffic: A re-read x64, B re-read x32 -> 4.2 GB total (-40% vs R10).
// 512 threads = 8 waves (2M x 4N), wave-tile 128x64 (4mi x 2ni of 32x32,
// acc 128 AGPR). LDS: 4 bufs x (A 16KB + B 16KB) = 128KB -> 1 block/CU.
//
// R13 FAILURE FIX: raw s_barrier is not a compiler fence; with 3 bufs the
// WAR window was ONE barrier and sunk ds_reads raced next tile's DMA writes.
// Now: (a) 4-buf rotation -> a buffer is rewritten only TWO barriers after
// its last read; (b) sched_barrier(0) immediately before AND after each
// s_barrier -> no instruction crosses a tile boundary (rule 18 discipline).
//
// Schedule per tile t (buf t&3, stage 2 ahead):
//   STAGE(t+2 -> buf (t+2)&3) [4 gload_lds]; vmcnt(4) [t+1 landed, t+2 in
//   flight]; COMPUTE(t) [12 ds_read_b128 lane-linear + 16 MFMA];
//   sched_barrier(0); s_barrier; sched_barrier(0).
// vmcnt FIFO (per wave): entry 4 outstanding (STAGE(t+1)); +4 = 8; vmcnt(4)
// drains STAGE(t+1). COMPUTE(t)'s operand STAGE(t) was drained one tile ago
// by every wave before it crossed the t-1 barrier -> cross-wave safe.
__global__ __launch_bounds__(512, 2) void gemm_i8_big4(
    const char* __restrict__ At, const char* __restrict__ Bt,
    const float* __restrict__ s, const float* __restrict__ bias,
    float* __restrict__ C) {
  __shared__ char lds[4][32768];  // [buf][A 16KB | B 16KB]

  // XCD swizzle: 2048 blocks (32 bm x 64 bn); per XCD one bn stripe
  // (8 bn x all 32 bm) = 256 contiguous wg.
  int bid = blockIdx.x;
  int wg = (bid & 7) * 256 + (bid >> 3);
  int bnS = wg >> 8;             // 0..7
  int rem = wg & 255;
  int bm = rem >> 3;             // 0..31
  int bn = bnS * 8 + (rem & 7);  // 0..63
  int rowBase = bm * 256;
  int colBase = bn * 256;

  int t = threadIdx.x;
  int lane = t & 63;
  int wave = t >> 6;
  int wr = wave >> 2;  // 0..1 -> M half (128)
  int wc = wave & 3;   // 0..3 -> N quarter (64)
  int l31 = lane & 31;
  int hi = lane >> 5;

  // staging sources: slab = 16 x 1KB chunks, chunk g = r32l*2 + ks;
  // thread t covers slots s = t and t+512 (slot s: g = s>>6, j = s&63).
  const char* gAp[2];
  const char* gBp[2];
#pragma unroll
  for (int q = 0; q < 2; ++q) {
    int ss = t + 512 * q;
    int g = ss >> 6;
    int r32l = g >> 1, ks = g & 1;
    int j = ss & 63;
    gAp[q] = At + ((size_t)((bm * 8 + r32l) * 128 + ks) << 10) + (j << 4);
    gBp[q] = Bt + ((size_t)((bn * 8 + r32l) * 128 + ks) << 10) + (j << 4);
  }

  i32x16 acc[4][2] = {};

#define STAGE(kt_, buf_)                                                      \
  {                                                                           \
    size_t _o = (size_t)(kt_) << 11;                                          \
    GLOAD_LDS16(gAp[0] + _o, &lds[buf_][t * 16]);                             \
    GLOAD_LDS16(gAp[1] + _o, &lds[buf_][8192 + t * 16]);                      \
    GLOAD_LDS16(gBp[0] + _o, &lds[buf_][16384 + t * 16]);                     \
    GLOAD_LDS16(gBp[1] + _o, &lds[buf_][24576 + t * 16]);                     \
  }
#define COMPUTE(buf_)                                                         \
  {                                                                           \
    const char* _la = &lds[buf_][0];                                          \
    const char* _lb = _la + 16384;                                            \
    _Pragma("unroll") for (int ks = 0; ks < 2; ++ks) {                        \
      i32x4 bf0 = *(const i32x4*)(_lb + (((wc * 2 + 0) * 2 + ks) << 10) +     \
                                  (lane << 4));                               \
      i32x4 bf1 = *(const i32x4*)(_lb + (((wc * 2 + 1) * 2 + ks) << 10) +     \
                                  (lane << 4));                               \
      _Pragma("unroll") for (int mi = 0; mi < 4; ++mi) {                      \
        i32x4 _af = *(const i32x4*)(_la + (((wr * 4 + mi) * 2 + ks) << 10) +  \
                                    (lane << 4));                             \
        acc[mi][0] = __builtin_amdgcn_mfma_i32_32x32x32_i8(                   \
            _af, bf0, acc[mi][0], 0, 0, 0);                                   \
        acc[mi][1] = __builtin_amdgcn_mfma_i32_32x32x32_i8(                   \
            _af, bf1, acc[mi][1], 0, 0, 0);                                   \
      }                                                                       \
    }                                                                         \
  }

  // prologue: tiles 0 and 1
  STAGE(0, 0);
  STAGE(1, 1);
  asm volatile("s_waitcnt vmcnt(4)" ::: "memory");  // tile0 landed
  __builtin_amdgcn_sched_barrier(0);
  __builtin_amdgcn_s_barrier();
  __builtin_amdgcn_sched_barrier(0);

  for (int tt = 0; tt < NT; ++tt) {
    int buf = tt & 3;
    if (tt + 2 < NT) {
      STAGE(tt + 2, (tt + 2) & 3);
      asm volatile("s_waitcnt vmcnt(4)" ::: "memory");  // tile t+1 landed
    } else if (tt + 1 < NT) {
      asm volatile("s_waitcnt vmcnt(0)" ::: "memory");  // drain last stage
    }
    COMPUTE(buf);
    __builtin_amdgcn_sched_barrier(0);  // nothing sinks past the barrier
    __builtin_amdgcn_s_barrier();
    __builtin_amdgcn_sched_barrier(0);  // nothing hoists above it
  }

#undef COMPUTE
#undef STAGE

  // epilogue: y = s[m] * acc + bias[n]
  // C/D 32x32: col = lane&31, row = (reg&3) + 8*(reg>>2) + 4*(lane>>5)
#pragma unroll
  for (int mi = 0; mi < 4; ++mi) {
#pragma unroll
    for (int ni = 0; ni < 2; ++ni) {
      int gc = colBase + wc * 64 + ni * 32 + l31;
      float bv = bias[gc];
#pragma unroll
      for (int rg = 0; rg < 16; ++rg) {
        int rowIn = (rg & 3) + 8 * (rg >> 2) + 4 * hi;
        int gr = rowBase + wr * 128 + mi * 32 + rowIn;
        C[(size_t)gr * N_TOT + gc] = (float)acc[mi][ni][rg] * s[gr] + bv;
      }
    }
  }
}

// ---------------- fallback (ws too small): fused bf16 conversion GEMM --------
__global__ void gemm_fused_kernel(const float* __restrict__ A,
                                  const float* __restrict__ W,
                                  const float* __restrict__ bias,
                                  float* __restrict__ C) {
  __shared__ ushort lsA[128 * 32];
  __shared__ ushort lsB[128 * 32];

  int nwg = gridDim.x;
  int bid = blockIdx.x;
  int wg = (bid & 7) * (nwg >> 3) + (bid >> 3);
  const int NBN = N_TOT / 128;
  int bm = wg / NBN;
  int bn = wg % NBN;
  int rowBase = bm * 128;
  int colBase = bn * 128;

  int t = threadIdx.x;
  int lane = t & 63;
  int wave = t >> 6;
  int wm = (wave >> 1) * 64;
  int wn = (wave & 1) * 64;

  f32x4 acc[4][4] = {};

  int srow = t >> 3;
  int scol = (t & 7) * 4;
  int fr = lane & 15;
  int koff = (lane >> 4) * 8;

  for (int k0 = 0; k0 < K_TOT; k0 += 32) {
    float4 va[4], vb[4];
#pragma unroll
    for (int r = 0; r < 4; ++r) {
      va[r] = *(const float4*)&A[(size_t)(rowBase + r * 32 + srow) * K_TOT + k0 + scol];
      vb[r] = *(const float4*)&W[(size_t)(colBase + r * 32 + srow) * K_TOT + k0 + scol];
    }
    __syncthreads();
#pragma unroll
    for (int r = 0; r < 4; ++r) {
      int e = r * 1024 + t * 4;
      ushort4 oa, ob;
      oa.x = f2bf_rne(va[r].x); oa.y = f2bf_rne(va[r].y);
      oa.z = f2bf_rne(va[r].z); oa.w = f2bf_rne(va[r].w);
      ob.x = sgn_bf16(vb[r].x); ob.y = sgn_bf16(vb[r].y);
      ob.z = sgn_bf16(vb[r].z); ob.w = sgn_bf16(vb[r].w);
      *(ushort4*)&lsA[e] = oa;
      *(ushort4*)&lsB[e] = ob;
    }
    __syncthreads();

    bf16x8 af[4], bfr[4];
#pragma unroll
    for (int i = 0; i < 4; ++i)
      af[i] = *(const bf16x8*)&lsA[(wm + i * 16 + fr) * 32 + koff];
#pragma unroll
    for (int j = 0; j < 4; ++j)
      bfr[j] = *(const bf16x8*)&lsB[(wn + j * 16 + fr) * 32 + koff];

#pragma unroll
    for (int i = 0; i < 4; ++i)
#pragma unroll
      for (int j = 0; j < 4; ++j)
        acc[i][j] = __builtin_amdgcn_mfma_f32_16x16x32_bf16(af[i], bfr[j],
                                                            acc[i][j], 0, 0, 0);
  }

  int orow0 = rowBase + wm + ((lane >> 4) << 2);
  int ocol0 = colBase + wn + (lane & 15);
#pragma unroll
  for (int i = 0; i < 4; ++i) {
#pragma unroll
    for (int j = 0; j < 4; ++j) {
      int col = ocol0 + j * 16;
      float bv = bias[col];
#pragma unroll
      for (int rg = 0; rg < 4; ++rg) {
        int row = orow0 + i * 16 + rg;
        C[(size_t)row * N_TOT + col] = acc[i][j][rg] + bv;
      }
    }
  }
}

extern "C" void kernel_launch(void* const* d_in, const int* in_sizes, int n_in,
                              void* d_out, int out_size, void* d_ws,
                              size_t ws_size, hipStream_t stream) {
  const float* x = (const float*)d_in[0];
  const float* W = (const float*)d_in[1];
  const float* b = (const float*)d_in[2];
  float* out = (float*)d_out;

  const size_t xq_bytes = (size_t)M_TOT * K_TOT;           // 33.5 MB
  const size_t wq_bytes = (size_t)N_TOT * K_TOT;           // 67.1 MB
  const size_t need = xq_bytes + wq_bytes + M_TOT * 4;     // ~101 MB

  if (ws_size >= need) {
    char* At = (char*)d_ws;
    char* Bt = At + xq_bytes;
    float* s = (float*)(Bt + wq_bytes);
    quant_x_kernel<<<M_TOT, 256, 0, stream>>>(x, At, s);
    quant_w_kernel<<<N_TOT / 32, 256, 0, stream>>>(W, Bt);
    const int nblocks = (M_TOT / 256) * (N_TOT / 256);  // 2048
    gemm_i8_big4<<<nblocks, 512, 0, stream>>>(At, Bt, s, b, out);
  } else {
    const int nblocks = (M_TOT / 128) * (N_TOT / 128);
    gemm_fused_kernel<<<nblocks, 256, 0, stream>>>(x, W, b, out);
  }
}